// Round 1
// baseline (22066.878 us; speedup 1.0000x reference)
//
#include <hip/hip_runtime.h>
#include <cstdint>
#include <cmath>

typedef unsigned short u16;
typedef __attribute__((ext_vector_type(8))) short short8;
typedef __attribute__((ext_vector_type(4))) float f32x4;

#define SEQ 1024
#define HD 1024
#define GD 4096
#define NB 8
#define MROWS 8192   // NB*SEQ
#define NWG 128
#define NU 8         // hidden units per workgroup

__device__ __forceinline__ u16 f2bf(float f) {
  union { float f; uint32_t u; } c; c.f = f;
  uint32_t u = c.u;
  uint32_t r = (u + 0x7fffu + ((u >> 16) & 1u)) >> 16;
  return (u16)r;
}
__device__ __forceinline__ float bf2f(u16 h) {
  union { uint32_t u; float f; } c; c.u = ((uint32_t)h) << 16;
  return c.f;
}

// ---------------- fp32 -> bf16 convert ----------------
__global__ void k_tobf16(const float* __restrict__ in, u16* __restrict__ out, long n) {
  long i = ((long)blockIdx.x * 256L + threadIdx.x) * 4;
  long st = (long)gridDim.x * 1024L;
  for (; i < n; i += st) {
    float4 v = *(const float4*)(in + i);
    ushort4 o;
    o.x = f2bf(v.x); o.y = f2bf(v.y); o.z = f2bf(v.z); o.w = f2bf(v.w);
    *(ushort4*)(out + i) = o;
  }
}

// ---------------- bf16 MFMA GEMM: C[m][n] = sum_k A[m][k]*Bw[n][k] (+epilogue) ----
// MODE 0: outb = bf16(acc + bias[n])
// MODE 1: outf = gelu(acc + bias[n]) + res[m][n]   (exact gelu)
template<int MODE>
__global__ __launch_bounds__(256, 1) void k_gemm(
    const u16* __restrict__ A, const u16* __restrict__ Bw,
    const float* __restrict__ bias, const float* __restrict__ res,
    u16* __restrict__ outb, float* __restrict__ outf, int N, int K)
{
  __shared__ u16 As[128][40];
  __shared__ u16 Bs[128][40];
  const int tid = threadIdx.x;
  const int wid = tid >> 6, lane = tid & 63;
  const int wm = wid >> 1, wn = wid & 1;
  const int r = lane & 15, q = lane >> 4;
  const long m0 = (long)blockIdx.y * 128, n0 = (long)blockIdx.x * 128;
  const int srow = tid >> 1, sseg = (tid & 1) * 16;

  f32x4 acc[4][4];
#pragma unroll
  for (int i = 0; i < 4; ++i)
#pragma unroll
    for (int j = 0; j < 4; ++j) acc[i][j] = (f32x4){0.f, 0.f, 0.f, 0.f};

  const u16* ag = A + (m0 + srow) * (long)K + sseg;
  const u16* bg = Bw + (n0 + srow) * (long)K + sseg;

  for (int k0 = 0; k0 < K; k0 += 32) {
    short8 av0 = *(const short8*)(ag + k0);
    short8 av1 = *(const short8*)(ag + k0 + 8);
    short8 bv0 = *(const short8*)(bg + k0);
    short8 bv1 = *(const short8*)(bg + k0 + 8);
    __syncthreads();
    *(short8*)&As[srow][sseg]     = av0;
    *(short8*)&As[srow][sseg + 8] = av1;
    *(short8*)&Bs[srow][sseg]     = bv0;
    *(short8*)&Bs[srow][sseg + 8] = bv1;
    __syncthreads();
    short8 bfr[4];
#pragma unroll
    for (int ni = 0; ni < 4; ++ni)
      bfr[ni] = *(const short8*)&Bs[wn * 64 + ni * 16 + r][q * 8];
#pragma unroll
    for (int mi = 0; mi < 4; ++mi) {
      short8 afr = *(const short8*)&As[wm * 64 + mi * 16 + r][q * 8];
#pragma unroll
      for (int ni = 0; ni < 4; ++ni)
        acc[mi][ni] = __builtin_amdgcn_mfma_f32_16x16x32_bf16(afr, bfr[ni], acc[mi][ni], 0, 0, 0);
    }
  }

#pragma unroll
  for (int mi = 0; mi < 4; ++mi)
#pragma unroll
    for (int ni = 0; ni < 4; ++ni) {
      long col = n0 + wn * 64 + ni * 16 + r;
      float bc = bias[col];
#pragma unroll
      for (int rr = 0; rr < 4; ++rr) {
        long row = m0 + wm * 64 + mi * 16 + q * 4 + rr;
        float v = acc[mi][ni][rr] + bc;
        if (MODE == 0) {
          outb[row * N + col] = f2bf(v);
        } else {
          float ge = 0.5f * v * (1.0f + erff(v * 0.70710678118654752f));
          outf[row * N + col] = ge + res[row * N + col];
        }
      }
    }
}

// ---------------- persistent sLSTM scan ----------------
// 128 WGs x 512 threads, 1/CU (108.5KB LDS). WG wg owns hidden units
// [wg*8, wg*8+8) for ALL 8 batches; 32 gate rows (col c = u*4+g) in LDS.
// Per step: stage h_{t-1} -> LDS, MFMA (batches = A rows 0..7), reduce,
// wave0 does exp-gated state update, store h to hseq, device barrier.
__global__ __launch_bounds__(512, 1) void k_scan(
    const u16* __restrict__ xp, const u16* __restrict__ Rb,
    u16* __restrict__ hseq, unsigned* __restrict__ bar)
{
  __shared__ u16 wgt[32 * 1024];      // [c][k], chunk-XOR-swizzled
  __shared__ u16 hA[16 * 1024];       // [row][k], rows 8..15 stay zero
  __shared__ float Dred[8][256];      // per-wave 16x16 partials
  __shared__ float xpf[2][NB][32];    // prefetched xp, [buf][b][g*8+u]

  const int tid = threadIdx.x;
  const int wg = blockIdx.x;
  const int wid = tid >> 6, lane = tid & 63;
  const int r = lane & 15, q = lane >> 4;

  // stage weights: c = tid>>4 (0..31), seg = tid&15; row c -> R row g*1024+wg*8+u
  {
    const int c = tid >> 4, seg = tid & 15;
    const int u = c >> 2, g = c & 3;
    const u16* src = Rb + ((long)(g * HD + wg * NU + u)) * HD + seg * 64;
#pragma unroll
    for (int j = 0; j < 8; ++j) {
      short8 v = *(const short8*)(src + j * 8);
      int chunk = seg * 8 + j;
      *(short8*)&wgt[c * 1024 + ((chunk ^ (c & 7)) << 3)] = v;
    }
  }
  // zero hA (16384 u16 = 2048 short8; 4 per thread)
#pragma unroll
  for (int j = 0; j < 4; ++j)
    *(short8*)&hA[(tid * 4 + j) * 8] = (short8){0, 0, 0, 0, 0, 0, 0, 0};

  // prologue: xp[t=0]
  if (tid < 32) {
    const int b = tid >> 2, g = tid & 3;
    short8 v = *(const short8*)(xp + ((long)(b * SEQ + 0)) * GD + g * HD + wg * NU);
#pragma unroll
    for (int u = 0; u < 8; ++u) xpf[0][b][g * 8 + u] = bf2f(((u16*)&v)[u]);
  }
  __syncthreads();

  float c_s = 0.f, n_s = 0.f, m_s = 0.f;

  for (int t = 0; t < SEQ; ++t) {
    // phase A: stage h_{t-1}; wave wid loads batch row wid
    if (t > 0) {
      const u16* hp = hseq + ((long)(wid * SEQ + (t - 1))) * HD + lane * 16;
      short8 v0 = *(const short8*)hp;
      short8 v1 = *(const short8*)(hp + 8);
      int ch = lane * 2;
      *(short8*)&hA[wid * 1024 + ((ch ^ (wid & 7)) << 3)]       = v0;
      *(short8*)&hA[wid * 1024 + (((ch + 1) ^ (wid & 7)) << 3)] = v1;
    }
    // phase A2: prefetch xp[t+1] (32 lanes of wave 0)
    if (tid < 32 && t + 1 < SEQ) {
      const int b = tid >> 2, g = tid & 3;
      short8 v = *(const short8*)(xp + ((long)(b * SEQ + t + 1)) * GD + g * HD + wg * NU);
#pragma unroll
      for (int u = 0; u < 8; ++u) xpf[(t + 1) & 1][b][g * 8 + u] = bf2f(((u16*)&v)[u]);
    }
    __syncthreads();

    // phase B: MFMA, wave wid = ct*4 + kq; D[b][c] = sum_k h[b][k]*R_row(c)[k]
    {
      const int ct = wid >> 2, kq = wid & 3;
      f32x4 d = (f32x4){0.f, 0.f, 0.f, 0.f};
#pragma unroll
      for (int kk = 0; kk < 8; ++kk) {
        int chunk = kq * 32 + kk * 4 + q;
        short8 a = *(const short8*)&hA[r * 1024 + ((chunk ^ (r & 7)) << 3)];
        int c = ct * 16 + r;
        short8 b = *(const short8*)&wgt[c * 1024 + ((chunk ^ (c & 7)) << 3)];
        d = __builtin_amdgcn_mfma_f32_16x16x32_bf16(a, b, d, 0, 0, 0);
      }
#pragma unroll
      for (int rr = 0; rr < 4; ++rr)
        Dred[wid][(q * 4 + rr) * 16 + r] = d[rr];
    }
    __syncthreads();

    // phase C: gates + state update (wave 0; lane = b*8+u)
    if (wid == 0) {
      const int b = lane >> 3, u = lane & 7;
      float pre[4];
#pragma unroll
      for (int g = 0; g < 4; ++g) {
        const int c = u * 4 + g;
        const int ctc = c >> 4, cc = c & 15;
        float s = xpf[t & 1][b][g * 8 + u];
#pragma unroll
        for (int k2 = 0; k2 < 4; ++k2) s += Dred[ctc * 4 + k2][b * 16 + cc];
        pre[g] = s;
      }
      float mn = fmaxf(pre[1] + m_s, pre[0]);
      float ig = __expf(pre[0] - mn);
      float fg = __expf(pre[1] + m_s - mn);
      c_s = fg * c_s + ig * tanhf(pre[2]);
      n_s = fg * n_s + ig;
      m_s = mn;
      float og = 1.0f / (1.0f + __expf(-pre[3]));
      float h = og * (c_s / n_s);
      hseq[((long)(b * SEQ + t)) * HD + wg * NU + u] = f2bf(h);
    }
    __syncthreads();

    // device-wide barrier (agent scope; handles cross-XCD L2 non-coherence)
    if (t < SEQ - 1) {
      if (tid == 0) {
        __threadfence();
        unsigned arrived = atomicAdd(&bar[0], 1u);
        if (arrived == NWG - 1) {
          __hip_atomic_store(&bar[0], 0u, __ATOMIC_RELAXED, __HIP_MEMORY_SCOPE_AGENT);
          __hip_atomic_fetch_add(&bar[1], 1u, __ATOMIC_RELEASE, __HIP_MEMORY_SCOPE_AGENT);
        } else {
          while (__hip_atomic_load(&bar[1], __ATOMIC_ACQUIRE, __HIP_MEMORY_SCOPE_AGENT) < (unsigned)(t + 1)) {
            __builtin_amdgcn_s_sleep(1);
          }
        }
        __threadfence();
      }
      __syncthreads();
    }
  }
}

// ---------------- row LayerNorm (D=1024), fp32 out + bf16 copy ----------------
__global__ __launch_bounds__(256, 1) void k_ln(
    const float* __restrict__ z, const float* __restrict__ gamma, const float* __restrict__ beta,
    float* __restrict__ xout, u16* __restrict__ xb)
{
  const int row = blockIdx.x, tid = threadIdx.x;
  const float4 v = *(const float4*)(z + (long)row * HD + tid * 4);
  float s = v.x + v.y + v.z + v.w;
  float s2 = v.x * v.x + v.y * v.y + v.z * v.z + v.w * v.w;
#pragma unroll
  for (int off = 32; off > 0; off >>= 1) {
    s += __shfl_down(s, off, 64);
    s2 += __shfl_down(s2, off, 64);
  }
  __shared__ float red[8];
  const int wid = tid >> 6, lane = tid & 63;
  if (lane == 0) { red[wid] = s; red[4 + wid] = s2; }
  __syncthreads();
  float su = red[0] + red[1] + red[2] + red[3];
  float sq = red[4] + red[5] + red[6] + red[7];
  float mu = su * (1.f / 1024.f);
  float var = sq * (1.f / 1024.f) - mu * mu;
  float rs = rsqrtf(var + 1e-5f);
  const float4 g  = *(const float4*)(gamma + tid * 4);
  const float4 bt = *(const float4*)(beta + tid * 4);
  float4 o;
  o.x = (v.x - mu) * rs * g.x + bt.x;
  o.y = (v.y - mu) * rs * g.y + bt.y;
  o.z = (v.z - mu) * rs * g.z + bt.z;
  o.w = (v.w - mu) * rs * g.w + bt.w;
  *(float4*)(xout + (long)row * HD + tid * 4) = o;
  ushort4 ob;
  ob.x = f2bf(o.x); ob.y = f2bf(o.y); ob.z = f2bf(o.z); ob.w = f2bf(o.w);
  *(ushort4*)(xb + (long)row * HD + tid * 4) = ob;
}

// ---------------- launch ----------------
extern "C" void kernel_launch(void* const* d_in, const int* in_sizes, int n_in,
                              void* d_out, int out_size, void* d_ws, size_t ws_size,
                              hipStream_t stream)
{
  const float* input = (const float*)d_in[0];
  const float* W[2]  = { (const float*)d_in[1], (const float*)d_in[8] };
  const float* R[2]  = { (const float*)d_in[2], (const float*)d_in[9] };
  const float* bb[2] = { (const float*)d_in[3], (const float*)d_in[10] };
  const float* pW[2] = { (const float*)d_in[4], (const float*)d_in[11] };
  const float* pb[2] = { (const float*)d_in[5], (const float*)d_in[12] };
  const float* gm[2] = { (const float*)d_in[6], (const float*)d_in[13] };
  const float* bt[2] = { (const float*)d_in[7], (const float*)d_in[14] };
  float* out = (float*)d_out;

  char* p = (char*)d_ws;
  size_t off = 0;
  auto alloc = [&](size_t bytes) { char* q = p + off; off += (bytes + 255) & ~(size_t)255; return (void*)q; };
  unsigned* bar = (unsigned*)alloc(256);
  u16* xb     = (u16*)alloc((size_t)MROWS * HD * 2);
  u16* Wb[2]  = { (u16*)alloc((size_t)GD * HD * 2), (u16*)alloc((size_t)GD * HD * 2) };
  u16* Rbv[2] = { (u16*)alloc((size_t)GD * HD * 2), (u16*)alloc((size_t)GD * HD * 2) };
  u16* pWb[2] = { (u16*)alloc((size_t)HD * HD * 2), (u16*)alloc((size_t)HD * HD * 2) };
  u16* xpb    = (u16*)alloc((size_t)MROWS * GD * 2);
  u16* hs     = (u16*)alloc((size_t)MROWS * HD * 2);
  float* zb   = (float*)alloc((size_t)MROWS * HD * 4);
  float* x1   = (float*)alloc((size_t)MROWS * HD * 4);

  auto conv = [&](const float* src, u16* dst, long n) {
    int blocks = (int)((n / 4 + 255) / 256); if (blocks > 2048) blocks = 2048;
    k_tobf16<<<dim3(blocks), dim3(256), 0, stream>>>(src, dst, n);
  };
  conv(input, xb, (long)MROWS * HD);
  conv(W[0], Wb[0], (long)GD * HD);  conv(W[1], Wb[1], (long)GD * HD);
  conv(R[0], Rbv[0], (long)GD * HD); conv(R[1], Rbv[1], (long)GD * HD);
  conv(pW[0], pWb[0], (long)HD * HD); conv(pW[1], pWb[1], (long)HD * HD);

  for (int l = 0; l < 2; ++l) {
    // xp = x @ W.T + b  -> bf16
    k_gemm<0><<<dim3(GD / 128, MROWS / 128), 256, 0, stream>>>(
        xb, Wb[l], bb[l], nullptr, xpb, nullptr, GD, HD);
    // sLSTM scan
    hipMemsetAsync(bar, 0, 64, stream);
    k_scan<<<dim3(NWG), dim3(512), 0, stream>>>(xpb, Rbv[l], hs, bar);
    // z = gelu(hseq @ pW.T + pb) + x_res
    const float* resp = (l == 0) ? input : x1;
    k_gemm<1><<<dim3(HD / 128, MROWS / 128), 256, 0, stream>>>(
        hs, pWb[l], pb[l], resp, nullptr, zb, HD, HD);
    // layernorm -> fp32 x_next (+ bf16 copy for next layer's GEMM1)
    float* xo = (l == 0) ? x1 : out;
    k_ln<<<dim3(MROWS), dim3(256), 0, stream>>>(zb, gm[l], bt[l], xo, xb);
  }
}

// Round 2
// 7246.149 us; speedup vs baseline: 3.0453x; 3.0453x over previous
//
#include <hip/hip_runtime.h>
#include <cstdint>
#include <cmath>

typedef unsigned short u16;
typedef unsigned long long u64;
typedef __attribute__((ext_vector_type(8))) short short8;
typedef __attribute__((ext_vector_type(4))) float f32x4;

#define SEQ 1024
#define HD 1024
#define GD 4096
#define NB 8
#define MROWS 8192   // NB*SEQ
#define NWG 128
#define NU 8         // hidden units per workgroup

__device__ __forceinline__ u16 f2bf(float f) {
  union { float f; uint32_t u; } c; c.f = f;
  uint32_t u = c.u;
  uint32_t r = (u + 0x7fffu + ((u >> 16) & 1u)) >> 16;
  return (u16)r;
}
__device__ __forceinline__ float bf2f(u16 h) {
  union { uint32_t u; float f; } c; c.u = ((uint32_t)h) << 16;
  return c.f;
}

// ---------------- fp32 -> bf16 convert ----------------
__global__ void k_tobf16(const float* __restrict__ in, u16* __restrict__ out, long n) {
  long i = ((long)blockIdx.x * 256L + threadIdx.x) * 4;
  long st = (long)gridDim.x * 1024L;
  for (; i < n; i += st) {
    float4 v = *(const float4*)(in + i);
    ushort4 o;
    o.x = f2bf(v.x); o.y = f2bf(v.y); o.z = f2bf(v.z); o.w = f2bf(v.w);
    *(ushort4*)(out + i) = o;
  }
}

// ---------------- bf16 MFMA GEMM: C[m][n] = sum_k A[m][k]*Bw[n][k] (+epilogue) ----
// MODE 0: outb[(t*8+b)*4096 + col] = bf16(acc + bias[n])   (t-major relayout for scan)
// MODE 1: outf = gelu(acc + bias[n]) + res[m][n]           (exact gelu)
template<int MODE>
__global__ __launch_bounds__(256, 1) void k_gemm(
    const u16* __restrict__ A, const u16* __restrict__ Bw,
    const float* __restrict__ bias, const float* __restrict__ res,
    u16* __restrict__ outb, float* __restrict__ outf, int N, int K)
{
  __shared__ u16 As[128][40];
  __shared__ u16 Bs[128][40];
  const int tid = threadIdx.x;
  const int wid = tid >> 6, lane = tid & 63;
  const int wm = wid >> 1, wn = wid & 1;
  const int r = lane & 15, q = lane >> 4;
  const long m0 = (long)blockIdx.y * 128, n0 = (long)blockIdx.x * 128;
  const int srow = tid >> 1, sseg = (tid & 1) * 16;

  f32x4 acc[4][4];
#pragma unroll
  for (int i = 0; i < 4; ++i)
#pragma unroll
    for (int j = 0; j < 4; ++j) acc[i][j] = (f32x4){0.f, 0.f, 0.f, 0.f};

  const u16* ag = A + (m0 + srow) * (long)K + sseg;
  const u16* bg = Bw + (n0 + srow) * (long)K + sseg;

  for (int k0 = 0; k0 < K; k0 += 32) {
    short8 av0 = *(const short8*)(ag + k0);
    short8 av1 = *(const short8*)(ag + k0 + 8);
    short8 bv0 = *(const short8*)(bg + k0);
    short8 bv1 = *(const short8*)(bg + k0 + 8);
    __syncthreads();
    *(short8*)&As[srow][sseg]     = av0;
    *(short8*)&As[srow][sseg + 8] = av1;
    *(short8*)&Bs[srow][sseg]     = bv0;
    *(short8*)&Bs[srow][sseg + 8] = bv1;
    __syncthreads();
    short8 bfr[4];
#pragma unroll
    for (int ni = 0; ni < 4; ++ni)
      bfr[ni] = *(const short8*)&Bs[wn * 64 + ni * 16 + r][q * 8];
#pragma unroll
    for (int mi = 0; mi < 4; ++mi) {
      short8 afr = *(const short8*)&As[wm * 64 + mi * 16 + r][q * 8];
#pragma unroll
      for (int ni = 0; ni < 4; ++ni)
        acc[mi][ni] = __builtin_amdgcn_mfma_f32_16x16x32_bf16(afr, bfr[ni], acc[mi][ni], 0, 0, 0);
    }
  }

#pragma unroll
  for (int mi = 0; mi < 4; ++mi)
#pragma unroll
    for (int ni = 0; ni < 4; ++ni) {
      long col = n0 + wn * 64 + ni * 16 + r;
      float bc = bias[col];
#pragma unroll
      for (int rr = 0; rr < 4; ++rr) {
        long row = m0 + wm * 64 + mi * 16 + q * 4 + rr;
        float v = acc[mi][ni][rr] + bc;
        if (MODE == 0) {
          long b = row >> 10, t = row & 1023;
          outb[((t * 8 + b) << 12) + col] = f2bf(v);
        } else {
          float ge = 0.5f * v * (1.0f + erff(v * 0.70710678118654752f));
          outf[row * N + col] = ge + res[row * N + col];
        }
      }
    }
}

// ---------------- persistent sLSTM scan ----------------
// 128 WGs x 512 threads, 1/CU (~110KB LDS). WG wg owns hidden units
// [wg*8, wg*8+8) for ALL 8 batches. h exchange via bypassing agent atomics
// (hx double buffer, straight to coherent L3 - no L2 flush/inv), handshake
// via per-WG padded monotonic flags (zero atomic contention).
__global__ __launch_bounds__(512, 1) void k_scan(
    const u16* __restrict__ xp, const u16* __restrict__ Rb,
    u16* __restrict__ hseq, u16* __restrict__ hx, unsigned* __restrict__ flags)
{
  __shared__ u16 wgt[32 * 1024];      // [c][k], chunk-XOR-swizzled
  __shared__ u16 hA[16 * 1024];       // [row][k], rows 8..15 stay zero
  __shared__ float Dred[8][256];      // per-wave 16x16 partials
  __shared__ float xpf[2][NB][32];    // prefetched xp, [buf][b][g*8+u]
  __shared__ u16 hhist[32 * 64];      // [t&31][b*8+u] staged h for hseq dump

  const int tid = threadIdx.x;
  const int wg = blockIdx.x;
  const int wid = tid >> 6, lane = tid & 63;
  const int r = lane & 15, q = lane >> 4;

  // stage weights: c = tid>>4 (0..31), seg = tid&15; row c -> R row g*1024+wg*8+u
  {
    const int c = tid >> 4, seg = tid & 15;
    const int u = c >> 2, g = c & 3;
    const u16* src = Rb + ((long)(g * HD + wg * NU + u)) * HD + seg * 64;
#pragma unroll
    for (int j = 0; j < 8; ++j) {
      short8 v = *(const short8*)(src + j * 8);
      int chunk = seg * 8 + j;
      *(short8*)&wgt[c * 1024 + ((chunk ^ (c & 7)) << 3)] = v;
    }
  }
  // zero hA
#pragma unroll
  for (int j = 0; j < 4; ++j)
    *(short8*)&hA[(tid * 4 + j) * 8] = (short8){0, 0, 0, 0, 0, 0, 0, 0};

  // prologue: xp[t=0]  (t-major layout: ((t*8+b)<<12) + g*1024 + wg*8)
  if (tid >= 64 && tid < 96) {
    const int b = (tid - 64) >> 2, g = (tid - 64) & 3;
    short8 v = *(const short8*)(xp + ((long)(0 * 8 + b) << 12) + g * HD + wg * NU);
#pragma unroll
    for (int u = 0; u < 8; ++u) xpf[0][b][g * 8 + u] = bf2f(((u16*)&v)[u]);
  }
  __syncthreads();

  float c_s = 0.f, n_s = 0.f, m_s = 0.f;

  for (int t = 0; t < SEQ; ++t) {
    // ---- phase A: stage h_{t-1} from hx (bypassing atomic loads -> coherent L3)
    if (t > 0) {
      const int ch = tid & 127;       // chunk of 8 u16
      const int b0 = tid >> 7;        // 0..3 ; also handles b0+4
      const u64* src = (const u64*)(hx + (((t - 1) & 1) << 13));
#pragma unroll
      for (int half = 0; half < 2; ++half) {
        const int b = b0 + half * 4;
        const u64* s1 = src + (b * 256 + ch * 2);
        union { u64 qv[2]; short8 v; } uu;
        uu.qv[0] = __hip_atomic_load(s1,     __ATOMIC_RELAXED, __HIP_MEMORY_SCOPE_AGENT);
        uu.qv[1] = __hip_atomic_load(s1 + 1, __ATOMIC_RELAXED, __HIP_MEMORY_SCOPE_AGENT);
        *(short8*)&hA[b * 1024 + ((ch ^ (b & 7)) << 3)] = uu.v;
      }
    }
    // phase A2: wave1 prefetches xp[t+1] (overlaps wave0's later gate math)
    if (tid >= 64 && tid < 96 && t + 1 < SEQ) {
      const int b = (tid - 64) >> 2, g = (tid - 64) & 3;
      short8 v = *(const short8*)(xp + ((long)((t + 1) * 8 + b) << 12) + g * HD + wg * NU);
#pragma unroll
      for (int u = 0; u < 8; ++u) xpf[(t + 1) & 1][b][g * 8 + u] = bf2f(((u16*)&v)[u]);
    }
    __syncthreads();

    // ---- phase B: MFMA, wave wid = ct*4 + kq; D[b][c] = sum_k h[b][k]*R_row(c)[k]
    {
      const int ct = wid >> 2, kq = wid & 3;
      f32x4 d = (f32x4){0.f, 0.f, 0.f, 0.f};
#pragma unroll
      for (int kk = 0; kk < 8; ++kk) {
        int chunk = kq * 32 + kk * 4 + q;
        short8 a = *(const short8*)&hA[r * 1024 + ((chunk ^ (r & 7)) << 3)];
        int c = ct * 16 + r;
        short8 b = *(const short8*)&wgt[c * 1024 + ((chunk ^ (c & 7)) << 3)];
        d = __builtin_amdgcn_mfma_f32_16x16x32_bf16(a, b, d, 0, 0, 0);
      }
#pragma unroll
      for (int rr = 0; rr < 4; ++rr)
        Dred[wid][(q * 4 + rr) * 16 + r] = d[rr];
    }
    __syncthreads();

    // ---- phase C: gates + state update (wave 0; lane = b*8+u)
    if (wid == 0) {
      const int b = lane >> 3, u = lane & 7;
      float pre[4];
#pragma unroll
      for (int g = 0; g < 4; ++g) {
        const int c = u * 4 + g;
        const int ctc = c >> 4, cc = c & 15;
        float s = xpf[t & 1][b][g * 8 + u];
#pragma unroll
        for (int k2 = 0; k2 < 4; ++k2) s += Dred[ctc * 4 + k2][b * 16 + cc];
        pre[g] = s;
      }
      float mn = fmaxf(pre[1] + m_s, pre[0]);
      float ig = __expf(pre[0] - mn);
      float fg = __expf(pre[1] + m_s - mn);
      c_s = fg * c_s + ig * tanhf(pre[2]);
      n_s = fg * n_s + ig;
      m_s = mn;
      float og = 1.0f / (1.0f + __expf(-pre[3]));
      float h = og * (c_s / n_s);

      unsigned hu = (unsigned)f2bf(h);
      hhist[(t & 31) * 64 + lane] = (u16)hu;           // stage for hseq dump
      // pack 4 lanes' u16 -> u64, bypassing store into hx[t&1]
      unsigned lo = hu | (__shfl_down(hu, 1) << 16);
      u64 v64 = (u64)lo | ((u64)__shfl_down(lo, 2) << 32);
      if ((lane & 3) == 0 && t < SEQ - 1) {
        u64* dst = (u64*)(hx + ((t & 1) << 13) + b * 1024 + wg * NU + u);
        __hip_atomic_store(dst, v64, __ATOMIC_RELAXED, __HIP_MEMORY_SCOPE_AGENT);
      }
      if (lane == 0 && t < SEQ - 1) {
        // order: hx store-acks reach coherence point, then publish flag
        asm volatile("s_waitcnt vmcnt(0)" ::: "memory");
        __hip_atomic_store(&flags[wg * 16], (unsigned)(t + 1),
                           __ATOMIC_RELAXED, __HIP_MEMORY_SCOPE_AGENT);
      }
    }
    __syncthreads();

    // ---- hseq dump every 32 steps (waves 4-7, regular stores, amortized)
    if ((t & 31) == 31 && tid >= 256) {
      const int idx = tid - 256;          // 0..255
      const int tt = idx >> 3, b = idx & 7;
      short8 v = *(const short8*)&hhist[tt * 64 + b * 8];
      *(short8*)(hseq + ((long)(b * SEQ + (t - 31 + tt))) * HD + wg * NU) = v;
    }

    // ---- distributed flag barrier: 128 lanes poll 128 per-WG flags
    if (t < SEQ - 1) {
      if (tid < NWG) {
        const unsigned tgt = (unsigned)(t + 1);
        while (__hip_atomic_load(&flags[tid * 16], __ATOMIC_RELAXED,
                                 __HIP_MEMORY_SCOPE_AGENT) < tgt) {}
      }
      __syncthreads();
    }
  }
}

// ---------------- row LayerNorm (D=1024), fp32 out + bf16 copy ----------------
__global__ __launch_bounds__(256, 1) void k_ln(
    const float* __restrict__ z, const float* __restrict__ gamma, const float* __restrict__ beta,
    float* __restrict__ xout, u16* __restrict__ xb)
{
  const int row = blockIdx.x, tid = threadIdx.x;
  const float4 v = *(const float4*)(z + (long)row * HD + tid * 4);
  float s = v.x + v.y + v.z + v.w;
  float s2 = v.x * v.x + v.y * v.y + v.z * v.z + v.w * v.w;
#pragma unroll
  for (int off = 32; off > 0; off >>= 1) {
    s += __shfl_down(s, off, 64);
    s2 += __shfl_down(s2, off, 64);
  }
  __shared__ float red[8];
  const int wid = tid >> 6, lane = tid & 63;
  if (lane == 0) { red[wid] = s; red[4 + wid] = s2; }
  __syncthreads();
  float su = red[0] + red[1] + red[2] + red[3];
  float sq = red[4] + red[5] + red[6] + red[7];
  float mu = su * (1.f / 1024.f);
  float var = sq * (1.f / 1024.f) - mu * mu;
  float rs = rsqrtf(var + 1e-5f);
  const float4 g  = *(const float4*)(gamma + tid * 4);
  const float4 bt = *(const float4*)(beta + tid * 4);
  float4 o;
  o.x = (v.x - mu) * rs * g.x + bt.x;
  o.y = (v.y - mu) * rs * g.y + bt.y;
  o.z = (v.z - mu) * rs * g.z + bt.z;
  o.w = (v.w - mu) * rs * g.w + bt.w;
  *(float4*)(xout + (long)row * HD + tid * 4) = o;
  ushort4 ob;
  ob.x = f2bf(o.x); ob.y = f2bf(o.y); ob.z = f2bf(o.z); ob.w = f2bf(o.w);
  *(ushort4*)(xb + (long)row * HD + tid * 4) = ob;
}

// ---------------- launch ----------------
extern "C" void kernel_launch(void* const* d_in, const int* in_sizes, int n_in,
                              void* d_out, int out_size, void* d_ws, size_t ws_size,
                              hipStream_t stream)
{
  const float* input = (const float*)d_in[0];
  const float* W[2]  = { (const float*)d_in[1], (const float*)d_in[8] };
  const float* R[2]  = { (const float*)d_in[2], (const float*)d_in[9] };
  const float* bb[2] = { (const float*)d_in[3], (const float*)d_in[10] };
  const float* pW[2] = { (const float*)d_in[4], (const float*)d_in[11] };
  const float* pb[2] = { (const float*)d_in[5], (const float*)d_in[12] };
  const float* gm[2] = { (const float*)d_in[6], (const float*)d_in[13] };
  const float* bt[2] = { (const float*)d_in[7], (const float*)d_in[14] };
  float* out = (float*)d_out;

  char* p = (char*)d_ws;
  size_t off = 0;
  auto alloc = [&](size_t bytes) { char* q = p + off; off += (bytes + 255) & ~(size_t)255; return (void*)q; };
  unsigned* flags = (unsigned*)alloc(NWG * 64);
  u16* hx     = (u16*)alloc(2 * NB * HD * 2);
  u16* xb     = (u16*)alloc((size_t)MROWS * HD * 2);
  u16* Wb[2]  = { (u16*)alloc((size_t)GD * HD * 2), (u16*)alloc((size_t)GD * HD * 2) };
  u16* Rbv[2] = { (u16*)alloc((size_t)GD * HD * 2), (u16*)alloc((size_t)GD * HD * 2) };
  u16* pWb[2] = { (u16*)alloc((size_t)HD * HD * 2), (u16*)alloc((size_t)HD * HD * 2) };
  u16* xpb    = (u16*)alloc((size_t)MROWS * GD * 2);
  u16* hs     = (u16*)alloc((size_t)MROWS * HD * 2);
  float* zb   = (float*)alloc((size_t)MROWS * HD * 4);
  float* x1   = (float*)alloc((size_t)MROWS * HD * 4);

  auto conv = [&](const float* src, u16* dst, long n) {
    int blocks = (int)((n / 4 + 255) / 256); if (blocks > 2048) blocks = 2048;
    k_tobf16<<<dim3(blocks), dim3(256), 0, stream>>>(src, dst, n);
  };
  conv(input, xb, (long)MROWS * HD);
  conv(W[0], Wb[0], (long)GD * HD);  conv(W[1], Wb[1], (long)GD * HD);
  conv(R[0], Rbv[0], (long)GD * HD); conv(R[1], Rbv[1], (long)GD * HD);
  conv(pW[0], pWb[0], (long)HD * HD); conv(pW[1], pWb[1], (long)HD * HD);

  for (int l = 0; l < 2; ++l) {
    // xp = x @ W.T + b  -> bf16, t-major layout
    k_gemm<0><<<dim3(GD / 128, MROWS / 128), 256, 0, stream>>>(
        xb, Wb[l], bb[l], nullptr, xpb, nullptr, GD, HD);
    // sLSTM scan
    hipMemsetAsync(flags, 0, NWG * 64, stream);
    k_scan<<<dim3(NWG), dim3(512), 0, stream>>>(xpb, Rbv[l], hs, hx, flags);
    // z = gelu(hseq @ pW.T + pb) + x_res
    const float* resp = (l == 0) ? input : x1;
    k_gemm<1><<<dim3(HD / 128, MROWS / 128), 256, 0, stream>>>(
        hs, pWb[l], pb[l], resp, nullptr, zb, HD, HD);
    // layernorm -> fp32 x_next (+ bf16 copy for next layer's GEMM1)
    float* xo = (l == 0) ? x1 : out;
    k_ln<<<dim3(MROWS), dim3(256), 0, stream>>>(zb, gm[l], bt[l], xo, xb);
  }
}